// Round 1
// baseline (398.894 us; speedup 1.0000x reference)
//
#include <hip/hip_runtime.h>
#include <math.h>

#define NB 512
#define ND 64
#define EPSF 1e-8f

// ---------------- Kernel 1: phases + complex linear projections ----------------
__global__ __launch_bounds__(64) void proj_kernel(
    const float* __restrict__ Zq, const float* __restrict__ Zk, const float* __restrict__ Zv,
    const float* __restrict__ tma,
    const float* __restrict__ Wq_w, const float* __restrict__ Wq_b,
    const float* __restrict__ Wk_w, const float* __restrict__ Wk_b,
    const float* __restrict__ Wv_w, const float* __restrict__ Wv_b,
    const float* __restrict__ lam_v,
    float* __restrict__ ef_r, float* __restrict__ ef_i,
    float* __restrict__ Uq_r, float* __restrict__ Uq_i,
    float* __restrict__ Uk_r, float* __restrict__ Uk_i,
    float* __restrict__ Uv_r, float* __restrict__ Uv_i,
    float* __restrict__ Vr_o, float* __restrict__ Vi_o,
    float* __restrict__ sumq, float* __restrict__ sumk,
    float* __restrict__ lam_out)
{
    const int bn = blockIdx.x;          // b*N + n
    const int b  = bn >> 9;
    const int n  = bn & (NB - 1);
    const int d  = threadIdx.x;         // 0..63

    __shared__ float zqr[ND], zqi[ND], zkr[ND], zki[ND], zvr[ND], zvi[ND];
    zqr[d] = Zq[((b*2 + 0)*NB + n)*ND + d];
    zqi[d] = Zq[((b*2 + 1)*NB + n)*ND + d];
    zkr[d] = Zk[((b*2 + 0)*NB + n)*ND + d];
    zki[d] = Zk[((b*2 + 1)*NB + n)*ND + d];
    zvr[d] = Zv[((b*2 + 0)*NB + n)*ND + d];
    zvi[d] = Zv[((b*2 + 1)*NB + n)*ND + d];
    __syncthreads();

    // lam_imag = concat([lam_v, -lam_v])
    const float lam = (d < 32) ? lam_v[d] : -lam_v[d - 32];
    const float t0    = tma[0];
    const float denom = tma[NB - 1] - t0;
    const float tn    = tma[n] / denom;
    const float ph  = tn * lam;
    const float efr = cosf(ph);
    const float efi = sinf(ph);

    if (b == 0) { ef_r[n*ND + d] = efr; ef_i[n*ND + d] = efi; }
    if (bn == 0) { lam_out[d] = 0.0f; lam_out[ND + d] = lam; }

    float qr = Wq_b[d], qi = Wq_b[ND + d];
    float kr = Wk_b[d], ki = Wk_b[ND + d];
    float vr = Wv_b[d], vi = Wv_b[ND + d];
    const int r0 = d * ND;          // W[0][d][:]
    const int r1 = ND*ND + d * ND;  // W[1][d][:]
    #pragma unroll 8
    for (int e = 0; e < ND; ++e) {
        const float w0q = Wq_w[r0 + e], w1q = Wq_w[r1 + e];
        qr += zqr[e]*w0q - zqi[e]*w1q;
        qi += zqr[e]*w1q + zqi[e]*w0q;
        const float w0k = Wk_w[r0 + e], w1k = Wk_w[r1 + e];
        kr += zkr[e]*w0k - zki[e]*w1k;
        ki += zkr[e]*w1k + zki[e]*w0k;
        const float w0v = Wv_w[r0 + e], w1v = Wv_w[r1 + e];
        vr += zvr[e]*w0v - zvi[e]*w1v;
        vi += zvr[e]*w1v + zvi[e]*w0v;
    }

    // U = conj(ef) * X   (eb = ef_r, -ef_i)
    const float uqr = efr*qr + efi*qi, uqi = efr*qi - efi*qr;
    const float ukr = efr*kr + efi*ki, uki = efr*ki - efi*kr;
    const float uvr = efr*vr + efi*vi, uvi = efr*vi - efi*vr;

    const int idx = bn*ND + d;
    Uq_r[idx] = uqr; Uq_i[idx] = uqi;
    Uk_r[idx] = ukr; Uk_i[idx] = uki;
    Uv_r[idx] = uvr; Uv_i[idx] = uvi;
    Vr_o[idx] = vr;  Vi_o[idx] = vi;

    // per-row |Uq|^2, |Uk|^2 sums (W2 = cos^2+sin^2 == 1)
    float q2 = uqr*uqr + uqi*uqi;
    float k2 = ukr*ukr + uki*uki;
    #pragma unroll
    for (int off = 32; off > 0; off >>= 1) {
        q2 += __shfl_down(q2, off);
        k2 += __shfl_down(k2, off);
    }
    if (d == 0) { sumq[bn] = q2; sumk[bn] = k2; }
}

// ---------------- Kernel 2: causal distance-attention per (b, i) ----------------
__global__ __launch_bounds__(256) void attn_kernel(
    const float* __restrict__ ef_r, const float* __restrict__ ef_i,
    const float* __restrict__ Uq_r, const float* __restrict__ Uq_i,
    const float* __restrict__ Uk_r, const float* __restrict__ Uk_i,
    const float* __restrict__ Uv_r, const float* __restrict__ Uv_i,
    const float* __restrict__ Vr,  const float* __restrict__ Vi,
    const float* __restrict__ sumq, const float* __restrict__ sumk,
    const float* __restrict__ tma,
    const float* __restrict__ eta_param,
    const float* __restrict__ s_lo, const float* __restrict__ s_lg,
    const float* __restrict__ s_nf, const float* __restrict__ s_tau,
    float* __restrict__ estl_out,   // d_out + 0
    float* __restrict__ Q_out,      // d_out + off_Q
    float* __restrict__ p_r, float* __restrict__ p_i)
{
    const int bi  = blockIdx.x;     // b*N + i
    const int b   = bi >> 9;
    const int i   = bi & (NB - 1);
    const int tid = threadIdx.x;    // 0..255

    __shared__ __align__(16) float sA[NB];
    __shared__ __align__(16) float qr_s[ND], qi_s[ND];
    __shared__ float red[256];
    __shared__ float erp[8][ND];

    const float t0    = tma[0];
    const float denom = tma[NB - 1] - t0;
    const float ti    = tma[i] / denom;
    const float lo    = s_lo[0] * s_lo[0];
    const float lg    = s_lg[0] * s_lg[0] + EPSF;
    const float nf2   = s_nf[0] * s_nf[0] + EPSF;
    const float tau2  = s_tau[0] * s_tau[0];
    const float t1    = sumq[bi];

    if (tid < ND) { qr_s[tid] = Uq_r[bi*ND + tid]; qi_s[tid] = Uq_i[bi*ND + tid]; }
    __syncthreads();

    // scores for j <= i
    float lmax = -INFINITY;
    for (int j = tid; j <= i; j += 256) {
        const float4* kr4 = (const float4*)&Uk_r[(b*NB + j)*ND];
        const float4* ki4 = (const float4*)&Uk_i[(b*NB + j)*ND];
        const float4* qr4 = (const float4*)qr_s;
        const float4* qi4 = (const float4*)qi_s;
        float dot = 0.0f;
        #pragma unroll
        for (int e = 0; e < ND/4; ++e) {
            const float4 kr = kr4[e], ki = ki4[e];
            const float4 qr = qr4[e], qi = qi4[e];
            dot += qr.x*kr.x + qr.y*kr.y + qr.z*kr.z + qr.w*kr.w
                 + qi.x*ki.x + qi.y*ki.y + qi.z*ki.z + qi.w*ki.w;
        }
        const float tj   = tma[j] / denom;
        const float vavg = lo * fabsf(ti - tj) + lg;
        const float base = nf2 * vavg + t1 + sumk[b*NB + j] - 2.0f*dot;
        const float sc   = -tau2 * logf(base);
        sA[j] = sc;
        lmax = fmaxf(lmax, sc);
    }

    // block max
    red[tid] = lmax; __syncthreads();
    for (int s = 128; s > 0; s >>= 1) {
        if (tid < s) red[tid] = fmaxf(red[tid], red[tid + s]);
        __syncthreads();
    }
    const float m = red[0];
    __syncthreads();

    // exp + block sum
    float lsum = 0.0f;
    for (int j = tid; j <= i; j += 256) {
        const float e = expf(sA[j] - m);
        sA[j] = e;
        lsum += e;
    }
    red[tid] = lsum; __syncthreads();
    for (int s = 128; s > 0; s >>= 1) {
        if (tid < s) red[tid] += red[tid + s];
        __syncthreads();
    }
    const float inv = 1.0f / red[0];
    __syncthreads();

    // write A row (real plane) + zero imag plane
    for (int j = tid; j < NB; j += 256) {
        float a = 0.0f;
        if (j <= i) { a = sA[j] * inv; sA[j] = a; }
        Q_out[((size_t)(b*2 + 0)*NB + i)*NB + j] = a;
        Q_out[((size_t)(b*2 + 1)*NB + i)*NB + j] = 0.0f;
    }
    __syncthreads();

    // er/ei = A @ Uv ; 4 waves split j, lanes are d
    const int lane = tid & 63;
    const int w    = tid >> 6;
    float er = 0.0f, ei = 0.0f;
    for (int j = w; j <= i; j += 4) {
        const float a = sA[j];
        er += a * Uv_r[(b*NB + j)*ND + lane];
        ei += a * Uv_i[(b*NB + j)*ND + lane];
    }
    erp[w][lane] = er; erp[4 + w][lane] = ei;
    __syncthreads();

    if (tid < ND) {
        const int d = tid;
        const float err = erp[0][d] + erp[1][d] + erp[2][d] + erp[3][d];
        const float eii = erp[4][d] + erp[5][d] + erp[6][d] + erp[7][d];
        const float efr = ef_r[i*ND + d], efi = ef_i[i*ND + d];
        const float estr = efr*err - efi*eii;
        const float esti = efr*eii + efi*err;
        const float eta  = 1.0f / (1.0f + expf(-eta_param[d]));
        const float g    = 1.0f / (1.0f + expf(-eta));
        const float vr   = Vr[bi*ND + d], vi = Vi[bi*ND + d];
        const float elr  = (1.0f - eta)*vr + g*estr;
        const float eli  = (1.0f - eta)*vi + g*esti;
        estl_out[((b*2 + 0)*NB + i)*ND + d] = elr;
        estl_out[((b*2 + 1)*NB + i)*ND + d] = eli;
        p_r[bi*ND + d] = efr*elr - efi*eli;
        p_i[bi*ND + d] = efr*eli + efi*elr;
    }
}

// ---------------- Kernel 3: output complex linear ----------------
__global__ __launch_bounds__(64) void outproj_kernel(
    const float* __restrict__ p_r, const float* __restrict__ p_i,
    const float* __restrict__ Wp_w, const float* __restrict__ Wp_b,
    float* __restrict__ out)
{
    const int bn = blockIdx.x;
    const int b  = bn >> 9;
    const int n  = bn & (NB - 1);
    const int d  = threadIdx.x;

    __shared__ float pr[ND], pi[ND];
    pr[d] = p_r[bn*ND + d];
    pi[d] = p_i[bn*ND + d];
    __syncthreads();

    float orr = Wp_b[d], oii = Wp_b[ND + d];
    const int r0 = d * ND;
    const int r1 = ND*ND + d * ND;
    #pragma unroll 8
    for (int e = 0; e < ND; ++e) {
        const float w0 = Wp_w[r0 + e], w1 = Wp_w[r1 + e];
        orr += pr[e]*w0 - pi[e]*w1;
        oii += pr[e]*w1 + pi[e]*w0;
    }
    out[((b*2 + 0)*NB + n)*ND + d] = orr;
    out[((b*2 + 1)*NB + n)*ND + d] = oii;
}

// ---------------- Kernel 4: Z_ij_hat_all — the 256 MB stream ----------------
__global__ __launch_bounds__(256) void zhat_kernel(
    const float* __restrict__ ef_r, const float* __restrict__ ef_i,
    const float* __restrict__ Uv_r, const float* __restrict__ Uv_i,
    float* __restrict__ Z_out)
{
    const int bi  = blockIdx.x;     // b*N + i
    const int b   = bi >> 9;
    const int i   = bi & (NB - 1);
    const int tid = threadIdx.x;

    __shared__ __align__(16) float efr_s[ND], efi_s[ND];
    if (tid < ND) { efr_s[tid] = ef_r[i*ND + tid]; efi_s[tid] = ef_i[i*ND + tid]; }
    __syncthreads();

    const int d0    = (tid * 4) & (ND - 1);   // float4 offset within row
    const int jbase = (tid * 4) >> 6;         // 0..15
    const float4 er4 = *(const float4*)&efr_s[d0];
    const float4 ei4 = *(const float4*)&efi_s[d0];

    const size_t base_r = ((size_t)(b*2 + 0)*NB + i) * (size_t)(NB*ND);
    const size_t base_i = ((size_t)(b*2 + 1)*NB + i) * (size_t)(NB*ND);

    for (int jg = 0; jg < NB; jg += 16) {
        const int j = jg + jbase;
        const float4 uvr = *(const float4*)&Uv_r[(b*NB + j)*ND + d0];
        const float4 uvi = *(const float4*)&Uv_i[(b*NB + j)*ND + d0];
        float4 zr, zi;
        zr.x = er4.x*uvr.x - ei4.x*uvi.x;  zi.x = er4.x*uvi.x + ei4.x*uvr.x;
        zr.y = er4.y*uvr.y - ei4.y*uvi.y;  zi.y = er4.y*uvi.y + ei4.y*uvr.y;
        zr.z = er4.z*uvr.z - ei4.z*uvi.z;  zi.z = er4.z*uvi.z + ei4.z*uvr.z;
        zr.w = er4.w*uvr.w - ei4.w*uvi.w;  zi.w = er4.w*uvi.w + ei4.w*uvr.w;
        const size_t off = (size_t)j*ND + d0;
        *(float4*)&Z_out[base_r + off] = zr;
        *(float4*)&Z_out[base_i + off] = zi;
    }
}

extern "C" void kernel_launch(void* const* d_in, const int* in_sizes, int n_in,
                              void* d_out, int out_size, void* d_ws, size_t ws_size,
                              hipStream_t stream) {
    const float* Zq   = (const float*)d_in[0];
    const float* Zk   = (const float*)d_in[1];
    const float* Zv   = (const float*)d_in[2];
    const float* tma  = (const float*)d_in[3];
    const float* Wq_w = (const float*)d_in[4];
    const float* Wq_b = (const float*)d_in[5];
    const float* Wk_w = (const float*)d_in[6];
    const float* Wk_b = (const float*)d_in[7];
    const float* Wv_w = (const float*)d_in[8];
    const float* Wv_b = (const float*)d_in[9];
    const float* Wp_w = (const float*)d_in[10];
    const float* Wp_b = (const float*)d_in[11];
    const float* lamv = (const float*)d_in[12];
    const float* s_lo = (const float*)d_in[13];
    const float* s_lg = (const float*)d_in[14];
    const float* s_nf = (const float*)d_in[15];
    const float* s_tau= (const float*)d_in[16];
    const float* etap = (const float*)d_in[17];

    float* out = (float*)d_out;
    // output offsets (floats), return order: est_latent, out, Q_ij, Z_ij_hat_all, lambda_h
    float* o_est = out;                       // 2*2*512*64   = 131072
    float* o_out = out + 131072;              // 131072
    float* o_Q   = out + 262144;              // 2*2*512*512  = 1048576
    float* o_Z   = out + 1310720;             // 2*2*512*512*64 = 67108864
    float* o_lam = out + 68419584;            // 128

    // workspace layout (floats)
    float* ws   = (float*)d_ws;
    float* ef_r = ws;            // 32768
    float* ef_i = ws + 32768;
    float* Uq_r = ws + 65536;    // each 65536
    float* Uq_i = ws + 131072;
    float* Uk_r = ws + 196608;
    float* Uk_i = ws + 262144;
    float* Uv_r = ws + 327680;
    float* Uv_i = ws + 393216;
    float* Vr   = ws + 458752;
    float* Vi   = ws + 524288;
    float* p_r  = ws + 589824;
    float* p_i  = ws + 655360;
    float* sumq = ws + 720896;   // 1024
    float* sumk = ws + 721920;   // 1024

    proj_kernel<<<2*NB, 64, 0, stream>>>(Zq, Zk, Zv, tma, Wq_w, Wq_b, Wk_w, Wk_b,
        Wv_w, Wv_b, lamv, ef_r, ef_i, Uq_r, Uq_i, Uk_r, Uk_i, Uv_r, Uv_i,
        Vr, Vi, sumq, sumk, o_lam);

    attn_kernel<<<2*NB, 256, 0, stream>>>(ef_r, ef_i, Uq_r, Uq_i, Uk_r, Uk_i,
        Uv_r, Uv_i, Vr, Vi, sumq, sumk, tma, etap, s_lo, s_lg, s_nf, s_tau,
        o_est, o_Q, p_r, p_i);

    outproj_kernel<<<2*NB, 64, 0, stream>>>(p_r, p_i, Wp_w, Wp_b, o_out);

    zhat_kernel<<<2*NB, 256, 0, stream>>>(ef_r, ef_i, Uv_r, Uv_i, o_Z);
}